// Round 17
// baseline (265.461 us; speedup 1.0000x reference)
//
#include <hip/hip_runtime.h>
#include <math.h>
#include <stdint.h>
#include <stddef.h>

#define N_NODES 8192
#define N_EDGES 524288
#define N_PAIRS 262144
#define N_TYPES 86
#define F1 128
#define F2 64

typedef unsigned short ushort_t;
typedef unsigned int uint_t;
typedef __attribute__((ext_vector_type(8))) short bfrag;
typedef __attribute__((ext_vector_type(4))) uint_t ufrag;
typedef __attribute__((ext_vector_type(4))) float ffrag;

typedef __attribute__((address_space(3))) char lds_char;
typedef __attribute__((address_space(1))) const char g_char;

__device__ __forceinline__ void gload16(const void* g, void* l) {
  __builtin_amdgcn_global_load_lds((const g_char*)g, (lds_char*)l, 16, 0, 0);
}

__device__ inline ushort_t f2bf(float f) {
  uint_t u = __float_as_uint(f);
  uint_t r = u + 0x7fffu + ((u >> 16) & 1u);
  return (ushort_t)(r >> 16);
}
__device__ inline float bf2f(ushort_t h) {
  return __uint_as_float(((uint_t)h) << 16);
}

// 8 consecutive fp32 -> packed bf16 fragment (RNE via v_cvt_pk_bf16_f32)
__device__ __forceinline__ bfrag cvtfrag(float4 a, float4 b) {
  uint_t h0, h1, h2, h3;
  asm("v_cvt_pk_bf16_f32 %0, %1, %2" : "=v"(h0) : "v"(a.x), "v"(a.y));
  asm("v_cvt_pk_bf16_f32 %0, %1, %2" : "=v"(h1) : "v"(a.z), "v"(a.w));
  asm("v_cvt_pk_bf16_f32 %0, %1, %2" : "=v"(h2) : "v"(b.x), "v"(b.y));
  asm("v_cvt_pk_bf16_f32 %0, %1, %2" : "=v"(h3) : "v"(b.z), "v"(b.w));
  ufrag u;
  u.x = h0; u.y = h1; u.z = h2; u.w = h3;
  return __builtin_bit_cast(bfrag, u);
}

// ---------------- degree / CSR build ----------------

__global__ void zero_k(int* __restrict__ p) {
  p[blockIdx.x * 256 + threadIdx.x] = 0;
}

__global__ void count_deg_k(const int* __restrict__ dst, int* __restrict__ cnt) {
  int e = blockIdx.x * blockDim.x + threadIdx.x;
  if (e < N_EDGES) atomicAdd(&cnt[dst[e]], 1);
}

__global__ void scan_k(const int* __restrict__ cnt, int* __restrict__ rp,
                       int* __restrict__ fill, float* __restrict__ dinv) {
  __shared__ int s[1024];
  int t = threadIdx.x;
  int v[8];
  int sum = 0;
#pragma unroll
  for (int i = 0; i < 8; i++) {
    v[i] = cnt[t * 8 + i];
    dinv[t * 8 + i] = 1.0f / sqrtf((float)(v[i] + 1));
    sum += v[i];
  }
  s[t] = sum;
  __syncthreads();
  for (int off = 1; off < 1024; off <<= 1) {
    int add = (t >= off) ? s[t - off] : 0;
    __syncthreads();
    s[t] += add;
    __syncthreads();
  }
  int excl = s[t] - sum;
#pragma unroll
  for (int i = 0; i < 8; i++) {
    rp[t * 8 + i] = excl;
    fill[t * 8 + i] = excl;
    excl += v[i];
  }
  if (t == 1023) rp[N_NODES] = excl;
}

__global__ void scatter_k(const int* __restrict__ src, const int* __restrict__ dst,
                          int* fill, int* __restrict__ csr) {
  int e = blockIdx.x * blockDim.x + threadIdx.x;
  if (e < N_EDGES) {
    int d = dst[e];
    int pos = atomicAdd(&fill[d], 1);
    csr[pos] = src[e];
  }
}

// ---------------- W1 transpose to bf16: W1t[n][k] = bf16(W1[k][n]) ----------------

__global__ __launch_bounds__(256) void w1t_k(const float* __restrict__ W1,
                                             ushort_t* __restrict__ W1t) {
  __shared__ ushort_t lh[32 * 65];
  int tid = threadIdx.x;
  int k0 = blockIdx.x * 64;
  int n0 = blockIdx.y * 32;
#pragma unroll
  for (int i = 0; i < 8; i++) {
    int c = tid + 256 * i;
    int kr = c >> 5, nc = c & 31;
    lh[nc * 65 + kr] = f2bf(W1[(size_t)(k0 + kr) * F1 + n0 + nc]);
  }
  __syncthreads();
  {
    int c = tid;  // 256 = 32 rows x 8 kc
    int nr = c >> 3, kc = c & 7;
    uint4 u;
    u.x = (uint_t)lh[nr * 65 + kc * 8 + 0] | ((uint_t)lh[nr * 65 + kc * 8 + 1] << 16);
    u.y = (uint_t)lh[nr * 65 + kc * 8 + 2] | ((uint_t)lh[nr * 65 + kc * 8 + 3] << 16);
    u.z = (uint_t)lh[nr * 65 + kc * 8 + 4] | ((uint_t)lh[nr * 65 + kc * 8 + 5] << 16);
    u.w = (uint_t)lh[nr * 65 + kc * 8 + 6] | ((uint_t)lh[nr * 65 + kc * 8 + 7] << 16);
    *(uint4*)(W1t + (size_t)(n0 + nr) * N_NODES + k0 + kc * 8) = u;
  }
}

// ---------------- GEMM1: per-lane direct A, depth-2 pipeline, 1 barrier/step ----------------
// 256 thr (4 waves 2Mx2N), BM=128, BN=128, BK=32, S=8 -> 512 blocks (2/CU).
// A: each lane loads ITS OWN MFMA fragment (8 consecutive fp32 of one x row),
//    converts in-register (cvt_pk RNE); NO A-LDS, NO A barrier. Depth-2 named
//    register sets (rule #20). B: global_load_lds 2-buffer (R16 mapping).
// vmcnt ledger (issue order B before A so counted waits skip deep A prefetch):
//   loop-top outstanding = [A(s+1):8]; issue B(s+1):2, A(s+2):8 -> 18;
//   WAITVM(10) drains A(s+1); WAITVM(8) drains B(s+1); ONE barrier.

#define BLDS(b) ((b) * 8192)

#define SCHED0 __builtin_amdgcn_sched_barrier(0)
#define WAITVM(N)  do { asm volatile("s_waitcnt vmcnt(" #N ")" ::: "memory"); SCHED0; } while (0)

__global__ __launch_bounds__(256, 2) void gemm1_mfma_k(const float* __restrict__ x,
                                                       const ushort_t* __restrict__ W1t,
                                                       float* __restrict__ part, int kspan) {
  __shared__ __align__(16) char lds[16384];
  int tid = threadIdx.x;
  int wave = tid >> 6, lane = tid & 63;
  int wr = wave >> 1, wc = wave & 1;
  int lrow = lane & 15, kgrp = lane >> 4;
  int m_blk = blockIdx.y * 128;
  int kbase = blockIdx.x * kspan;
  int ktiles = kspan >> 5;  // 32
  int s0 = (5 * blockIdx.y + 3 * blockIdx.x) & (ktiles - 1);  // rotation

  // per-lane A base pointers (fragment: 8 consecutive floats of one row)
  const float* ap0 = x + (size_t)(m_blk + wr * 64 + 0 * 16 + lrow) * N_NODES + kgrp * 8;
  const float* ap1 = x + (size_t)(m_blk + wr * 64 + 1 * 16 + lrow) * N_NODES + kgrp * 8;
  const float* ap2 = x + (size_t)(m_blk + wr * 64 + 2 * 16 + lrow) * N_NODES + kgrp * 8;
  const float* ap3 = x + (size_t)(m_blk + wr * 64 + 3 * 16 + lrow) * N_NODES + kgrp * 8;

  // B gload constants (R16 verbatim)
  int bq = wave;
  int b_row = bq * 32 + (lane >> 2);
  int b_kel = ((lane & 3) ^ ((lane >> 2) & 3)) << 3;

  ffrag acc[4][4];
#pragma unroll
  for (int mi = 0; mi < 4; mi++)
#pragma unroll
    for (int ni = 0; ni < 4; ni++) acc[mi][ni] = (ffrag)(0.0f);

  float4 sP[8], sQ[8];  // depth-2 A staging, named sets (static indexing)
  bfrag afr[4];

#define ISSUE_A(KO, SET)                                                             \
  {                                                                                  \
    SET[0] = *(const float4*)(ap0 + (KO));                                           \
    SET[1] = *(const float4*)(ap0 + (KO) + 4);                                       \
    SET[2] = *(const float4*)(ap1 + (KO));                                           \
    SET[3] = *(const float4*)(ap1 + (KO) + 4);                                       \
    SET[4] = *(const float4*)(ap2 + (KO));                                           \
    SET[5] = *(const float4*)(ap2 + (KO) + 4);                                       \
    SET[6] = *(const float4*)(ap3 + (KO));                                           \
    SET[7] = *(const float4*)(ap3 + (KO) + 4);                                       \
  }

#define CONV(SET)                                                                    \
  {                                                                                  \
    afr[0] = cvtfrag(SET[0], SET[1]);                                                \
    afr[1] = cvtfrag(SET[2], SET[3]);                                                \
    afr[2] = cvtfrag(SET[4], SET[5]);                                                \
    afr[3] = cvtfrag(SET[6], SET[7]);                                                \
  }

#define ISSUE_B(K0, BSEL)                                                            \
  {                                                                                  \
    _Pragma("unroll") for (int i = 0; i < 2; i++) {                                  \
      const ushort_t* gp = W1t + (size_t)(b_row + i * 16) * N_NODES + (K0) + b_kel;  \
      gload16(gp, lds + BLDS(BSEL) + bq * 2048 + i * 1024);                          \
    }                                                                                \
  }

#define COMPUTE(BSEL)                                                                \
  {                                                                                  \
    bfrag bh[4];                                                                     \
    _Pragma("unroll") for (int ni = 0; ni < 4; ni++) {                               \
      int brow = wc * 64 + ni * 16 + lrow;                                           \
      uint_t boff = brow * 64 + ((kgrp ^ (brow & 3)) << 4);                          \
      bh[ni] = *(const bfrag*)(lds + BLDS(BSEL) + boff);                             \
    }                                                                                \
    _Pragma("unroll") for (int mi = 0; mi < 4; mi++) {                               \
      _Pragma("unroll") for (int ni = 0; ni < 4; ni++) {                             \
        acc[mi][ni] = __builtin_amdgcn_mfma_f32_16x16x32_bf16(afr[mi], bh[ni], acc[mi][ni], 0, 0, 0); \
      }                                                                              \
    }                                                                                \
  }

#define NXT(p) ((p) + 1 == ktiles ? 0 : (p) + 1)

  // -------- prologue: queue = [A(s0):8][B(s0):2][A(s0+1):8] --------
  int p1 = s0;
  int p2 = NXT(p1);
  ISSUE_A(kbase + (p1 << 5), sP);
  SCHED0;
  ISSUE_B(kbase + (p1 << 5), 0);
  SCHED0;
  ISSUE_A(kbase + (p2 << 5), sQ);
  WAITVM(10);  // A(s0) regs
  CONV(sP);
  WAITVM(8);   // B(s0) in LDS, A(s0+1) stays in flight
  __builtin_amdgcn_s_barrier();
  SCHED0;

  // -------- main loop: 2 steps per iteration (ktiles even) --------
  for (int it = 0; it < ktiles; it += 2) {
    {  // even step: compute buf0 with afr(=A(s)); convert sQ (A(s+1))
      int pB = NXT(p1), pA = NXT(pB);
      ISSUE_B(kbase + (pB << 5), 1);
      SCHED0;
      ISSUE_A(kbase + (pA << 5), sP);
      SCHED0;
      __builtin_amdgcn_s_setprio(1);
      COMPUTE(0);
      __builtin_amdgcn_s_setprio(0);
      WAITVM(10);  // drain A(s+1)
      CONV(sQ);
      WAITVM(8);   // drain B(s+1); A(s+2) stays
      __builtin_amdgcn_s_barrier();
      SCHED0;
      p1 = pB;
    }
    {  // odd step
      int pB = NXT(p1), pA = NXT(pB);
      ISSUE_B(kbase + (pB << 5), 0);
      SCHED0;
      ISSUE_A(kbase + (pA << 5), sQ);
      SCHED0;
      __builtin_amdgcn_s_setprio(1);
      COMPUTE(1);
      __builtin_amdgcn_s_setprio(0);
      WAITVM(10);
      CONV(sP);
      WAITVM(8);
      __builtin_amdgcn_s_barrier();
      SCHED0;
      p1 = pB;
    }
  }

  // -------- epilogue: C[row=(lane>>4)*4+r][col=lane&15] per 16x16 frag --------
  float* outp = part + (size_t)blockIdx.x * (N_NODES * F1);
#pragma unroll
  for (int mi = 0; mi < 4; mi++) {
#pragma unroll
    for (int ni = 0; ni < 4; ni++) {
      int col = wc * 64 + ni * 16 + lrow;
#pragma unroll
      for (int r = 0; r < 4; r++) {
        int row = m_blk + wr * 64 + mi * 16 + kgrp * 4 + r;
        outp[(size_t)row * F1 + col] = acc[mi][ni][r];
      }
    }
  }
#undef ISSUE_A
#undef CONV
#undef ISSUE_B
#undef COMPUTE
#undef NXT
}

// in-place safe: each thread reads all S parts at its index, then writes part[0].
__global__ void reduceS_k(const float* __restrict__ part, float* __restrict__ xw1, int S) {
  int i = blockIdx.x * blockDim.x + threadIdx.x;
  float4 a = ((const float4*)part)[i];
  for (int s = 1; s < S; s++) {
    float4 b = ((const float4*)(part + (size_t)s * N_NODES * F1))[i];
    a.x += b.x; a.y += b.y; a.z += b.z; a.w += b.w;
  }
  ((float4*)xw1)[i] = a;
}

// ---------------- aggregation (gather over CSR) + bias + relu (R15 form) ----------------

template <int F>
__global__ void agg_k(const float* __restrict__ xw, const int* __restrict__ csr,
                      const int* __restrict__ rp, const float* __restrict__ dinv,
                      const float* __restrict__ bias, float* __restrict__ hout) {
  int node = blockIdx.x;
  int f = threadIdx.x;
  __shared__ int sidx[F];
  __shared__ float sdv[F];
  int beg = rp[node], end = rp[node + 1];
  float acc = 0.f;
  for (int base = beg; base < end; base += F) {
    int n = end - base;
    if (n > F) n = F;
    __syncthreads();
    if (f < n) {
      int s = csr[base + f];
      sidx[f] = s;
      sdv[f] = dinv[s];
    }
    __syncthreads();
    for (int i = 0; i < n; i++) acc += xw[(size_t)sidx[i] * F + f] * sdv[i];
  }
  float dv = dinv[node];
  float v = (acc + xw[(size_t)node * F + f] * dv) * dv + bias[f];
  hout[(size_t)node * F + f] = v > 0.f ? v : 0.f;
}

// ---------------- GEMM2: h1[8192,128] @ W2[128,64] ----------------

__global__ __launch_bounds__(256) void gemm2_k(const float* __restrict__ h1,
                                               const float* __restrict__ W2,
                                               float* __restrict__ xw2) {
  __shared__ float W2s[F1 * F2];
  __shared__ float As[16 * F1];
  int tid = threadIdx.x;
  int r0 = blockIdx.x * 16;
#pragma unroll
  for (int j = 0; j < 8; j++)
    ((float4*)W2s)[tid + 256 * j] = ((const float4*)W2)[tid + 256 * j];
#pragma unroll
  for (int j = 0; j < 2; j++)
    ((float4*)As)[tid + 256 * j] = ((const float4*)(h1 + (size_t)r0 * F1))[tid + 256 * j];
  __syncthreads();
  int r = tid >> 4, c4 = tid & 15;
  float4 acc = make_float4(0.f, 0.f, 0.f, 0.f);
#pragma unroll 8
  for (int k = 0; k < F1; k++) {
    float a = As[r * F1 + k];
    float4 bv = *(float4*)&W2s[k * F2 + 4 * c4];
    acc.x += a * bv.x; acc.y += a * bv.y; acc.z += a * bv.z; acc.w += a * bv.w;
  }
  *(float4*)&xw2[(size_t)(r0 + r) * F2 + 4 * c4] = acc;
}

// ---------------- P tables: P[i][0:86]=h2[i]@Wfc[:64], P[i][86:172]=h2[i]@Wfc[64:] ----------------

__global__ void pboth_k(const float* __restrict__ h2, const float* __restrict__ Wfc,
                        float* __restrict__ P) {
  __shared__ float hs[64 * 16];
  int tid = threadIdx.x;  // 192
  int r0 = blockIdx.x * 16;
  for (int idx = tid; idx < 256; idx += 192) {
    int row = idx >> 4, k4 = idx & 15;
    float4 h = *(const float4*)&h2[(size_t)(r0 + row) * F2 + 4 * k4];
    hs[(4 * k4 + 0) * 16 + row] = h.x;
    hs[(4 * k4 + 1) * 16 + row] = h.y;
    hs[(4 * k4 + 2) * 16 + row] = h.z;
    hs[(4 * k4 + 3) * 16 + row] = h.w;
  }
  __syncthreads();
  if (tid < 172) {
    int half = tid < 86 ? 0 : 1;
    int j = tid - 86 * half;
    const float* wp = Wfc + (size_t)(64 * half) * N_TYPES + j;
    float acc[16];
#pragma unroll
    for (int r = 0; r < 16; r++) acc[r] = 0.f;
    for (int k = 0; k < 64; k++) {
      float w = wp[(size_t)k * N_TYPES];
      const float* hk = &hs[k * 16];
#pragma unroll
      for (int r = 0; r < 16; r++) acc[r] += hk[r] * w;
    }
#pragma unroll
    for (int r = 0; r < 16; r++) P[(size_t)(r0 + r) * 172 + tid] = acc[r];
  }
}

// ---------------- final: out[p][t] = sigmoid(P1[d1[p]][t] + P2[d2[p]][t] + bfc[t]) ----------------

__global__ void final_k(const float* __restrict__ P, const int* __restrict__ d1,
                        const int* __restrict__ d2, const float* __restrict__ bfc,
                        float* __restrict__ out) {
  int gid = blockIdx.x * blockDim.x + threadIdx.x;
  if (gid >= N_PAIRS * 43) return;
  int p = gid / 43;
  int j = gid - p * 43;
  int a = d1[p], b = d2[p];
  float2 v1 = *(const float2*)&P[(size_t)a * 172 + 2 * j];
  float2 v2 = *(const float2*)&P[(size_t)b * 172 + 86 + 2 * j];
  float2 bb = *(const float2*)&bfc[2 * j];
  float z0 = v1.x + v2.x + bb.x;
  float z1 = v1.y + v2.y + bb.y;
  float2 o;
  o.x = 1.0f / (1.0f + expf(-z0));
  o.y = 1.0f / (1.0f + expf(-z1));
  *(float2*)&out[(size_t)p * 86 + 2 * j] = o;
}

// ---------------- launch ----------------

extern "C" void kernel_launch(void* const* d_in, const int* in_sizes, int n_in,
                              void* d_out, int out_size, void* d_ws, size_t ws_size,
                              hipStream_t stream) {
  const float* x   = (const float*)d_in[0];
  const int*   ei  = (const int*)d_in[1];
  const int*   d1  = (const int*)d_in[2];
  const int*   d2  = (const int*)d_in[3];
  const float* W1  = (const float*)d_in[4];
  const float* b1  = (const float*)d_in[5];
  const float* W2  = (const float*)d_in[6];
  const float* b2  = (const float*)d_in[7];
  const float* Wfc = (const float*)d_in[8];
  const float* bfc = (const float*)d_in[9];
  float* out = (float*)d_out;

  const int* esrc = ei;
  const int* edst = ei + N_EDGES;

  char* w = (char*)d_ws;
  size_t off = 0;
  auto alloc = [&](size_t bytes) -> char* {
    char* p = w + off;
    off += (bytes + 255) & ~(size_t)255;
    return p;
  };
  int*      cnt  = (int*)alloc((size_t)N_NODES * 4);
  float*    dinv = (float*)alloc((size_t)N_NODES * 4);
  int*      rp   = (int*)alloc((size_t)(N_NODES + 1) * 4);
  int*      fill = (int*)alloc((size_t)N_NODES * 4);
  int*      csr  = (int*)alloc((size_t)N_EDGES * 4);
  ushort_t* W1t  = (ushort_t*)alloc((size_t)N_NODES * F1 * 2);
  float*    h1   = (float*)alloc((size_t)N_NODES * F1 * 4);
  float*    xw2  = (float*)alloc((size_t)N_NODES * F2 * 4);
  float*    h2   = (float*)alloc((size_t)N_NODES * F2 * 4);
  float*    P    = (float*)alloc((size_t)N_NODES * 172 * 4);

  size_t partBytes = (size_t)N_NODES * F1 * 4;  // 4MB per split
  int S = 8;
  while (S > 1 && off + (size_t)S * partBytes > ws_size) S >>= 1;
  float* part = (float*)alloc((size_t)S * partBytes);
  float* xw1 = part;  // alias; reduceS_k is index-aligned in-place safe
  if (off > ws_size) return;

  zero_k<<<N_NODES / 256, 256, 0, stream>>>(cnt);
  count_deg_k<<<N_EDGES / 256, 256, 0, stream>>>(edst, cnt);
  scan_k<<<1, 1024, 0, stream>>>(cnt, rp, fill, dinv);
  scatter_k<<<N_EDGES / 256, 256, 0, stream>>>(esrc, edst, fill, csr);

  w1t_k<<<dim3(N_NODES / 64, F1 / 32), 256, 0, stream>>>(W1, W1t);
  // grid (S, M-blocks of 128): wgid%S == K-slice -> per-XCD B-slice L2 locality
  gemm1_mfma_k<<<dim3(S, N_NODES / 128), 256, 0, stream>>>(x, W1t, part, N_NODES / S);
  if (S > 1)
    reduceS_k<<<(N_NODES * F1 / 4) / 256, 256, 0, stream>>>(part, xw1, S);
  agg_k<F1><<<N_NODES, F1, 0, stream>>>(xw1, csr, rp, dinv, b1, h1);

  gemm2_k<<<N_NODES / 16, 256, 0, stream>>>(h1, W2, xw2);
  agg_k<F2><<<N_NODES, F2, 0, stream>>>(xw2, csr, rp, dinv, b2, h2);

  pboth_k<<<N_NODES / 16, 192, 0, stream>>>(h2, Wfc, P);
  final_k<<<(N_PAIRS * 43 + 255) / 256, 256, 0, stream>>>(P, d1, d2, bfc, out);
}